// Round 6
// baseline (254.050 us; speedup 1.0000x reference)
//
#include <hip/hip_runtime.h>
#include <hip/hip_bf16.h>

#define DIM 256
#define BATCH 8
#define SEQ 4096
#define MTOT (BATCH*SEQ)
#define LDP 40  // padded LDS row stride in bf16 elems (32 data + 8 pad) -> 2-way bank aliasing only (free, m136)

typedef __attribute__((ext_vector_type(8))) short bf16x8;
typedef __attribute__((ext_vector_type(4))) float f32x4;
typedef __attribute__((ext_vector_type(8))) unsigned short u16x8;
typedef __attribute__((ext_vector_type(4))) unsigned short u16x4;

__device__ inline unsigned short f2b(float f){
  unsigned int u = __float_as_uint(f);
  u = u + 0x7FFFu + ((u >> 16) & 1u);   // RNE
  return (unsigned short)(u >> 16);
}
__device__ inline float b2f(unsigned short h){
  return __uint_as_float(((unsigned int)h) << 16);
}

// Stage a 128x32 tile (row-major, k-contiguous) into padded LDS [128][LDP].
// 256 threads: thread t -> row t>>1, k-half t&1 (16 elems = 32B each).
template<bool F32SRC>
__device__ inline void stage_tile(const void* src, int ld, int tid, unsigned short* lds){
  int row = tid >> 1, kh = tid & 1;
  unsigned short tmp[16];
  if constexpr (F32SRC) {
    const float* p = (const float*)src + (long)row*ld + kh*16;
    #pragma unroll
    for (int j = 0; j < 16; j += 4){
      f32x4 f = *(const f32x4*)(p + j);
      tmp[j+0] = f2b(f[0]); tmp[j+1] = f2b(f[1]);
      tmp[j+2] = f2b(f[2]); tmp[j+3] = f2b(f[3]);
    }
  } else {
    const unsigned short* p = (const unsigned short*)src + (long)row*ld + kh*16;
    *(u16x8*)&tmp[0] = *(const u16x8*)p;
    *(u16x8*)&tmp[8] = *(const u16x8*)(p + 8);
  }
  unsigned short* d = lds + row*LDP + kh*16;
  *(u16x8*)d       = *(u16x8*)&tmp[0];
  *(u16x8*)(d + 8) = *(u16x8*)&tmp[8];
}

// One BK=32 step: 4 waves (2x2), each wave owns a 64x64 sub-tile -> 4x4 frags.
__device__ inline void mma_step(const unsigned short* lA, const unsigned short* lB,
                                int lane, int wr, int wc, f32x4 acc[4][4]){
  int r0 = lane & 15, ko = (lane >> 4) * 8;
  bf16x8 af[4], bf[4];
  #pragma unroll
  for (int m = 0; m < 4; m++) af[m] = *(const bf16x8*)&lA[(wr*64 + m*16 + r0)*LDP + ko];
  #pragma unroll
  for (int n = 0; n < 4; n++) bf[n] = *(const bf16x8*)&lB[(wc*64 + n*16 + r0)*LDP + ko];
  #pragma unroll
  for (int m = 0; m < 4; m++)
    #pragma unroll
    for (int n = 0; n < 4; n++)
      acc[m][n] = __builtin_amdgcn_mfma_f32_16x16x32_bf16(af[m], bf[n], acc[m][n], 0, 0, 0);
}

// Wt[s][n][k] = Ws[k][n]  (bf16, B^T layout; s: 0=Wq 1=Wk 2=Wv)
__global__ __launch_bounds__(256) void prep_wt(const float* __restrict__ Wq, const float* __restrict__ Wk,
                                               const float* __restrict__ Wv, unsigned short* __restrict__ Wt){
  int i = blockIdx.x*256 + threadIdx.x;          // 0..196607
  int s = i >> 16, r = i & 65535, n = r & 255, kk = r >> 8;
  const float* W = (s == 0) ? Wq : ((s == 1) ? Wk : Wv);
  Wt[s*65536 + n*256 + kk] = f2b(W[kk*256 + n]);
}

// All three projections in one dispatch.
// grid (lt 0..31, dt 0..1, bz 0..23): sel = bz%3 (0=K,1=V,2=Q), b = bz/3.
// sel 0/1: D[d_out][l] = sum_k W[k][d_out] * X[l][k]  (transposed output Kt/Vt)
//   A = Wt_s (rows=d_out, k-contig), B^T = X (rows=l, k-contig)
// sel 2:   Q[l][d_out]  (natural output)
//   A = X (rows=l), B^T = Wt_q (rows=d_out); Q M-tile index = b*32+lt (MTOT rows)
__global__ __launch_bounds__(256) void proj_all_ker(const float* __restrict__ qin, const float* __restrict__ kin,
                                                    const float* __restrict__ vin,
                                                    const unsigned short* __restrict__ Wt,
                                                    const float* __restrict__ bqp, const float* __restrict__ bkp,
                                                    const float* __restrict__ bvp,
                                                    unsigned short* __restrict__ Qo,
                                                    unsigned short* __restrict__ Kt, unsigned short* __restrict__ Vt,
                                                    float* __restrict__ ksum){
  __shared__ unsigned short lA[128*LDP], lB[128*LDP];
  int lt = blockIdx.x, dt = blockIdx.y;
  int bz = blockIdx.z, sel = bz % 3, b = bz / 3;
  int tid = threadIdx.x, lane = tid & 63, w = tid >> 6, wr = w >> 1, wc = w & 1;

  const float* X = (sel == 0 ? kin : (sel == 1 ? vin : qin)) + ((long)b*SEQ + (long)lt*128)*DIM;
  const unsigned short* Wb = Wt + ((sel + 1) % 3)*DIM*DIM + dt*128*DIM;   // K->Wk(1), V->Wv(2), Q->Wq(0)
  const float* bias = (sel == 0 ? bkp : (sel == 1 ? bvp : bqp));

  f32x4 acc[4][4] = {};
  for (int ks = 0; ks < DIM/32; ks++){
    __syncthreads();
    if (sel == 2){
      stage_tile<true >(X  + ks*32, DIM, tid, lA);
      stage_tile<false>(Wb + ks*32, DIM, tid, lB);
    } else {
      stage_tile<false>(Wb + ks*32, DIM, tid, lA);
      stage_tile<true >(X  + ks*32, DIM, tid, lB);
    }
    __syncthreads();
    mma_step(lA, lB, lane, wr, wc, acc);
  }
  int r0 = lane & 15, rg = lane >> 4;

  if (sel == 2){
    // acc rows = l (within this 128-row tile), cols = d_out
    #pragma unroll
    for (int n = 0; n < 4; n++){
      int col = dt*128 + wc*64 + n*16 + r0;
      float bv = bias[col];
      #pragma unroll
      for (int m = 0; m < 4; m++){
        #pragma unroll
        for (int r = 0; r < 4; r++){
          long row = (long)b*SEQ + lt*128 + wr*64 + m*16 + rg*4 + r;   // global token index
          float vv = acc[m][n][r] + bv;
          vv = vv > 0.f ? vv + 1.f : expf(vv);   // elu+1
          Qo[row*DIM + col] = f2b(vv);
        }
      }
    }
    return;
  }

  // sel 0/1: acc rows = d_out, cols = l
  unsigned short* Yt = (sel == 1 ? Vt : Kt) + (long)b*DIM*SEQ;
  float sums[4][4];
  #pragma unroll
  for (int m = 0; m < 4; m++) for (int r = 0; r < 4; r++) sums[m][r] = 0.f;
  #pragma unroll
  for (int m = 0; m < 4; m++){
    #pragma unroll
    for (int r = 0; r < 4; r++){
      int row = dt*128 + wr*64 + m*16 + rg*4 + r;     // d_out
      float bvv = bias[row];
      #pragma unroll
      for (int n = 0; n < 4; n++){
        int col = lt*128 + wc*64 + n*16 + r0;          // l
        float vv = acc[m][n][r] + bvv;
        if (sel == 0) vv = vv > 0.f ? vv + 1.f : expf(vv);
        Yt[(long)row*SEQ + col] = f2b(vv);
        sums[m][r] += vv;
      }
    }
  }
  if (sel == 0){
    #pragma unroll
    for (int m = 0; m < 4; m++){
      #pragma unroll
      for (int r = 0; r < 4; r++){
        float s = sums[m][r];
        s += __shfl_xor(s, 1); s += __shfl_xor(s, 2);
        s += __shfl_xor(s, 4); s += __shfl_xor(s, 8);
        if (r0 == 0){
          int row = dt*128 + wr*64 + m*16 + rg*4 + r;
          atomicAdd(&ksum[b*DIM + row], s);
        }
      }
    }
  }
}

// kvt[h][d] = sum_l Vt[h][l] * Kt[d][l]  (split-K over l, fp32 atomics)
// grid: (x = 2x2 tile, y = ksplit 0..15 (256 l each), z = b)
__global__ __launch_bounds__(256) void kv_ker(const unsigned short* __restrict__ Vt, const unsigned short* __restrict__ Kt,
                                              float* __restrict__ kvf){
  __shared__ unsigned short lA[128*LDP], lB[128*LDP];
  int qd = blockIdx.x, mt = qd >> 1, nt = qd & 1;
  int ksp = blockIdx.y, b = blockIdx.z;
  int tid = threadIdx.x, lane = tid & 63, w = tid >> 6, wr = w >> 1, wc = w & 1;
  const unsigned short* A  = Vt + (long)b*DIM*SEQ + (long)mt*128*SEQ + ksp*256;
  const unsigned short* Bb = Kt + (long)b*DIM*SEQ + (long)nt*128*SEQ + ksp*256;
  f32x4 acc[4][4] = {};
  for (int ks = 0; ks < 8; ks++){
    __syncthreads();
    stage_tile<false>(A  + ks*32, SEQ, tid, lA);
    stage_tile<false>(Bb + ks*32, SEQ, tid, lB);
    __syncthreads();
    mma_step(lA, lB, lane, wr, wc, acc);
  }
  int r0 = lane & 15, rg = lane >> 4;
  float* base = kvf + (long)b*DIM*DIM;
  #pragma unroll
  for (int m = 0; m < 4; m++)
    #pragma unroll
    for (int n = 0; n < 4; n++)
      #pragma unroll
      for (int r = 0; r < 4; r++){
        int row = mt*128 + wr*64 + m*16 + rg*4 + r;   // h
        int col = nt*128 + wc*64 + n*16 + r0;         // d
        atomicAdd(&base[row*DIM + col], acc[m][n][r]);
      }
}

// z[g] = dot(Q[g,:], ksum[b,:]) + 1e-6 ; one wave per row
__global__ __launch_bounds__(256) void zker(const unsigned short* __restrict__ Q, const float* __restrict__ ksum,
                                            float* __restrict__ z){
  int g = blockIdx.x*4 + (threadIdx.x >> 6);
  int lane = threadIdx.x & 63;
  int b = g >> 12;
  u16x4 qv = *(const u16x4*)(Q + (long)g*DIM + lane*4);
  const float* kp = ksum + b*DIM + lane*4;
  float s = b2f(qv[0])*kp[0] + b2f(qv[1])*kp[1] + b2f(qv[2])*kp[2] + b2f(qv[3])*kp[3];
  #pragma unroll
  for (int o = 1; o < 64; o <<= 1) s += __shfl_xor(s, o);
  if (lane == 0) z[g] = s + 1e-6f;
}

// out[g][h] = (sum_d Q[g][d]*kvt[h][d]) / z[g]   (fp32 out)
// B operand staged straight from the fp32 split-K accumulator kvf (bf16-converted during staging).
__global__ __launch_bounds__(256) void out_ker(const unsigned short* __restrict__ Q, const float* __restrict__ kvf,
                                               const float* __restrict__ z, float* __restrict__ out){
  __shared__ unsigned short lA[128*LDP], lB[128*LDP];
  int lt = blockIdx.x, ht = blockIdx.y, b = blockIdx.z;
  int tid = threadIdx.x, lane = tid & 63, w = tid >> 6, wr = w >> 1, wc = w & 1;
  const unsigned short* A = Q + ((long)b*SEQ + (long)lt*128)*DIM;
  const float* Bb = kvf + b*DIM*DIM + ht*128*DIM;
  f32x4 acc[4][4] = {};
  for (int ks = 0; ks < DIM/32; ks++){
    __syncthreads();
    stage_tile<false>(A  + ks*32, DIM, tid, lA);
    stage_tile<true >(Bb + ks*32, DIM, tid, lB);
    __syncthreads();
    mma_step(lA, lB, lane, wr, wc, acc);
  }
  int r0 = lane & 15, rg = lane >> 4;
  #pragma unroll
  for (int m = 0; m < 4; m++){
    #pragma unroll
    for (int r = 0; r < 4; r++){
      long g = (long)b*SEQ + lt*128 + wr*64 + m*16 + rg*4 + r;
      float inv = 1.0f / z[g];
      #pragma unroll
      for (int n = 0; n < 4; n++){
        int col = ht*128 + wc*64 + n*16 + r0;
        out[g*DIM + col] = acc[m][n][r] * inv;
      }
    }
  }
}

extern "C" void kernel_launch(void* const* d_in, const int* in_sizes, int n_in,
                              void* d_out, int out_size, void* d_ws, size_t ws_size,
                              hipStream_t stream){
  const float* q  = (const float*)d_in[0];
  const float* k  = (const float*)d_in[1];
  const float* v  = (const float*)d_in[2];
  const float* Wq = (const float*)d_in[3];
  const float* bq = (const float*)d_in[4];
  const float* Wk = (const float*)d_in[5];
  const float* bk = (const float*)d_in[6];
  const float* Wv = (const float*)d_in[7];
  const float* bv = (const float*)d_in[8];
  float* out = (float*)d_out;

  char* ws = (char*)d_ws;
  size_t off = 0;
  auto alloc = [&](size_t bytes){ void* p = ws + off; off += (bytes + 255) & ~(size_t)255; return p; };
  unsigned short* Q   = (unsigned short*)alloc((size_t)MTOT*DIM*2);        // 16 MiB
  unsigned short* Kt  = (unsigned short*)alloc((size_t)BATCH*DIM*SEQ*2);   // 16 MiB
  unsigned short* Vt  = (unsigned short*)alloc((size_t)BATCH*DIM*SEQ*2);   // 16 MiB
  unsigned short* Wt  = (unsigned short*)alloc((size_t)3*DIM*DIM*2);
  float*          kvf = (float*)alloc((size_t)BATCH*DIM*DIM*4);            // 2 MiB
  float*          ksum= (float*)alloc((size_t)BATCH*DIM*4);                // contiguous after kvf
  float*          zb  = (float*)alloc((size_t)MTOT*4);

  // zero the accumulated buffers (ws is poisoned 0xAA before every call)
  hipMemsetAsync(kvf, 0, (size_t)BATCH*DIM*DIM*4 + (size_t)BATCH*DIM*4, stream);

  hipLaunchKernelGGL(prep_wt,     dim3(768),     dim3(256), 0, stream, Wq, Wk, Wv, Wt);
  hipLaunchKernelGGL(proj_all_ker,dim3(32,2,24), dim3(256), 0, stream, q, k, v, Wt, bq, bk, bv, Q, Kt, Vt, ksum);
  hipLaunchKernelGGL(kv_ker,      dim3(4,16,8),  dim3(256), 0, stream, Vt, Kt, kvf);
  hipLaunchKernelGGL(zker,        dim3(8192),    dim3(256), 0, stream, Q, ksum, zb);
  hipLaunchKernelGGL(out_ker,     dim3(32,2,8),  dim3(256), 0, stream, Q, kvf, zb, out);
}

// Round 7
// 235.527 us; speedup vs baseline: 1.0786x; 1.0786x over previous
//
#include <hip/hip_runtime.h>
#include <hip/hip_bf16.h>

#define DIM 256
#define BATCH 8
#define SEQ 4096
#define MTOT (BATCH*SEQ)
#define NSPLIT 8   // kv split-K factor (512 l per split)

typedef __attribute__((ext_vector_type(8))) short bf16x8;
typedef __attribute__((ext_vector_type(4))) float f32x4;
typedef __attribute__((ext_vector_type(8))) unsigned short u16x8;
typedef __attribute__((ext_vector_type(4))) unsigned short u16x4;

__device__ inline unsigned short f2b(float f){
  unsigned int u = __float_as_uint(f);
  u = u + 0x7FFFu + ((u >> 16) & 1u);   // RNE
  return (unsigned short)(u >> 16);
}
__device__ inline float b2f(unsigned short h){
  return __uint_as_float(((unsigned int)h) << 16);
}

// ---------------------------------------------------------------------------
// LDS tile: [128 rows][128 bf16] = 32 KB, linear rows (256 B) with XOR swizzle
// byte_in_row ^= (row&7)<<4  applied on BOTH ds_write and ds_read (rule #21).
// Breaks the 256B-row same-bank column (G4) -> <=2-way aliasing (free, m136).
// ---------------------------------------------------------------------------

// Issue the global loads for one 128x128 half-tile (K-half h of 256).
// thread t -> row t>>1, 64-elem chunk t&1. F32 path: 16x16B loads; bf16: 8x16B.
template<bool F32>
__device__ inline void load_half(const void* src, int ld, int h, int tid,
                                 f32x4* vf, u16x8* vh){
  int row = tid >> 1, c0 = h*128 + (tid & 1)*64;
  if constexpr (F32){
    const float* p = (const float*)src + (long)row*ld + c0;
    #pragma unroll
    for (int j = 0; j < 16; j++) vf[j] = *(const f32x4*)(p + 4*j);
  } else {
    const unsigned short* p = (const unsigned short*)src + (long)row*ld + c0;
    #pragma unroll
    for (int j = 0; j < 8; j++) vh[j] = *(const u16x8*)(p + 8*j);
  }
}

// Convert (if fp32) and write the half-tile to LDS with the XOR swizzle.
template<bool F32>
__device__ inline void write_half(const f32x4* vf, const u16x8* vh, int tid,
                                  unsigned short* lds){
  unsigned short tmp[64];
  if constexpr (F32){
    #pragma unroll
    for (int j = 0; j < 16; j++){
      f32x4 f = vf[j];
      tmp[4*j+0] = f2b(f[0]); tmp[4*j+1] = f2b(f[1]);
      tmp[4*j+2] = f2b(f[2]); tmp[4*j+3] = f2b(f[3]);
    }
  } else {
    #pragma unroll
    for (int j = 0; j < 8; j++) *(u16x8*)&tmp[8*j] = vh[j];
  }
  int row = tid >> 1, sw = (row & 7) << 4;
  char* rb = (char*)lds + row*256 + (tid & 1)*128;
  #pragma unroll
  for (int j = 0; j < 8; j++)
    *(u16x8*)(rb + ((j*16) ^ sw)) = *(const u16x8*)&tmp[8*j];
}

// MFMA over one 128-wide K-half: 4 ksubs x 16 mfma (wave owns 64x64 subtile).
__device__ inline void mma_half(const unsigned short* lA, const unsigned short* lB,
                                int lane, int wr, int wc, f32x4 acc[4][4]){
  int r0 = lane & 15, kg16 = (lane >> 4) * 16;   // byte offset of k-group in row
  #pragma unroll
  for (int ksub = 0; ksub < 4; ksub++){
    int kb = ksub*64 + kg16;
    bf16x8 af[4], bf[4];
    #pragma unroll
    for (int m = 0; m < 4; m++){
      int row = wr*64 + m*16 + r0;
      af[m] = *(const bf16x8*)((const char*)lA + row*256 + (kb ^ ((row & 7) << 4)));
    }
    #pragma unroll
    for (int n = 0; n < 4; n++){
      int row = wc*64 + n*16 + r0;
      bf[n] = *(const bf16x8*)((const char*)lB + row*256 + (kb ^ ((row & 7) << 4)));
    }
    #pragma unroll
    for (int m = 0; m < 4; m++)
      #pragma unroll
      for (int n = 0; n < 4; n++)
        acc[m][n] = __builtin_amdgcn_mfma_f32_16x16x32_bf16(af[m], bf[n], acc[m][n], 0, 0, 0);
  }
}

// K=256 chunk, 128x128 output tile/block, BK=128 two-phase, cross-half register
// prefetch (T14: half-1 loads issued before half-0's MFMA, written after).
template<bool AF32, bool BF32>
__device__ inline void gemm256(const void* A, int lda, const void* B, int ldb,
                               int tid, int lane, int wr, int wc,
                               unsigned short* lA, unsigned short* lB,
                               f32x4 acc[4][4]){
  f32x4 a0f[16], a1f[16], b0f[16], b1f[16];
  u16x8 a0h[8], a1h[8], b0h[8], b1h[8];
  load_half<AF32>(A, lda, 0, tid, a0f, a0h);
  load_half<BF32>(B, ldb, 0, tid, b0f, b0h);
  __syncthreads();                              // prev readers done with LDS
  write_half<AF32>(a0f, a0h, tid, lA);
  write_half<BF32>(b0f, b0h, tid, lB);
  load_half<AF32>(A, lda, 1, tid, a1f, a1h);    // prefetch: in flight during mma
  load_half<BF32>(B, ldb, 1, tid, b1f, b1h);
  __syncthreads();
  mma_half(lA, lB, lane, wr, wc, acc);
  __syncthreads();
  write_half<AF32>(a1f, a1h, tid, lA);
  write_half<BF32>(b1f, b1h, tid, lB);
  __syncthreads();
  mma_half(lA, lB, lane, wr, wc, acc);
}

// Wt[s][n][k] = Ws[k][n]  (bf16, B^T layout; s: 0=Wq 1=Wk 2=Wv)
__global__ __launch_bounds__(256) void prep_wt(const float* __restrict__ Wq, const float* __restrict__ Wk,
                                               const float* __restrict__ Wv, unsigned short* __restrict__ Wt){
  int i = blockIdx.x*256 + threadIdx.x;
  int s = i >> 16, r = i & 65535, n = r & 255, kk = r >> 8;
  const float* W = (s == 0) ? Wq : ((s == 1) ? Wk : Wv);
  Wt[s*65536 + n*256 + kk] = f2b(W[kk*256 + n]);
}

// All three projections. grid (lt 0..31, dt 0..1, bz 0..23): sel=bz%3 (0=K,1=V,2=Q), b=bz/3.
__global__ __launch_bounds__(256) void proj_all_ker(const float* __restrict__ qin, const float* __restrict__ kin,
                                                    const float* __restrict__ vin,
                                                    const unsigned short* __restrict__ Wt,
                                                    const float* __restrict__ bqp, const float* __restrict__ bkp,
                                                    const float* __restrict__ bvp,
                                                    unsigned short* __restrict__ Qo,
                                                    unsigned short* __restrict__ Kt, unsigned short* __restrict__ Vt,
                                                    float* __restrict__ ksum){
  __shared__ unsigned short lA[128*128], lB[128*128];
  int lt = blockIdx.x, dt = blockIdx.y;
  int bz = blockIdx.z, sel = bz % 3, b = bz / 3;
  int tid = threadIdx.x, lane = tid & 63, w = tid >> 6, wr = w >> 1, wc = w & 1;

  const float* X = (sel == 0 ? kin : (sel == 1 ? vin : qin)) + ((long)b*SEQ + (long)lt*128)*DIM;
  const unsigned short* Wb = Wt + ((sel + 1) % 3)*DIM*DIM + dt*128*DIM;   // K->Wk, V->Wv, Q->Wq
  const float* bias = (sel == 0 ? bkp : (sel == 1 ? bvp : bqp));

  f32x4 acc[4][4] = {};
  if (sel == 2) gemm256<true , false>(X , DIM, Wb, DIM, tid, lane, wr, wc, lA, lB, acc);
  else          gemm256<false, true >(Wb, DIM, X , DIM, tid, lane, wr, wc, lA, lB, acc);

  int r0 = lane & 15, rg = lane >> 4;

  if (sel == 2){
    // acc rows = l, cols = d_out
    #pragma unroll
    for (int n = 0; n < 4; n++){
      int col = dt*128 + wc*64 + n*16 + r0;
      float bv = bias[col];
      #pragma unroll
      for (int m = 0; m < 4; m++)
        #pragma unroll
        for (int r = 0; r < 4; r++){
          long row = (long)b*SEQ + lt*128 + wr*64 + m*16 + rg*4 + r;
          float vv = acc[m][n][r] + bv;
          vv = vv > 0.f ? vv + 1.f : expf(vv);   // elu+1
          Qo[row*DIM + col] = f2b(vv);
        }
    }
    return;
  }

  // sel 0/1: acc rows = d_out, cols = l  (transposed outputs Kt/Vt)
  unsigned short* Yt = (sel == 1 ? Vt : Kt) + (long)b*DIM*SEQ;
  float sums[4][4];
  #pragma unroll
  for (int m = 0; m < 4; m++) for (int r = 0; r < 4; r++) sums[m][r] = 0.f;
  #pragma unroll
  for (int m = 0; m < 4; m++)
    #pragma unroll
    for (int r = 0; r < 4; r++){
      int row = dt*128 + wr*64 + m*16 + rg*4 + r;
      float bvv = bias[row];
      #pragma unroll
      for (int n = 0; n < 4; n++){
        int col = lt*128 + wc*64 + n*16 + r0;
        float vv = acc[m][n][r] + bvv;
        if (sel == 0) vv = vv > 0.f ? vv + 1.f : expf(vv);
        Yt[(long)row*SEQ + col] = f2b(vv);
        sums[m][r] += vv;
      }
    }
  if (sel == 0){
    #pragma unroll
    for (int m = 0; m < 4; m++)
      #pragma unroll
      for (int r = 0; r < 4; r++){
        float s = sums[m][r];
        s += __shfl_xor(s, 1); s += __shfl_xor(s, 2);
        s += __shfl_xor(s, 4); s += __shfl_xor(s, 8);
        if (r0 == 0){
          int row = dt*128 + wr*64 + m*16 + rg*4 + r;
          atomicAdd(&ksum[b*DIM + row], s);
        }
      }
  }
}

// kv partials: kvp[ksp][b][h][d] = sum over 512 l. NO atomics (was the ~100us tail).
// grid (x = 2x2 tile, y = ksp 0..7, z = b)
__global__ __launch_bounds__(256) void kv_ker(const unsigned short* __restrict__ Vt, const unsigned short* __restrict__ Kt,
                                              float* __restrict__ kvp){
  __shared__ unsigned short lA[128*128], lB[128*128];
  int qd = blockIdx.x, mt = qd >> 1, nt = qd & 1;
  int ksp = blockIdx.y, b = blockIdx.z;
  int tid = threadIdx.x, lane = tid & 63, w = tid >> 6, wr = w >> 1, wc = w & 1;
  const unsigned short* A = Vt + (long)b*DIM*SEQ + (long)mt*128*SEQ + ksp*512;
  const unsigned short* B = Kt + (long)b*DIM*SEQ + (long)nt*128*SEQ + ksp*512;
  f32x4 acc[4][4] = {};
  gemm256<false,false>(A      , SEQ, B      , SEQ, tid, lane, wr, wc, lA, lB, acc);
  gemm256<false,false>(A + 256, SEQ, B + 256, SEQ, tid, lane, wr, wc, lA, lB, acc);
  int r0 = lane & 15, rg = lane >> 4;
  float* base = kvp + (long)(ksp*BATCH + b)*DIM*DIM;
  #pragma unroll
  for (int m = 0; m < 4; m++)
    #pragma unroll
    for (int n = 0; n < 4; n++)
      #pragma unroll
      for (int r = 0; r < 4; r++){
        int row = mt*128 + wr*64 + m*16 + rg*4 + r;   // h
        int col = nt*128 + wc*64 + n*16 + r0;         // d
        base[row*DIM + col] = acc[m][n][r];
      }
}

// kvb[b][h][d] (bf16) = sum of NSPLIT fp32 partials
__global__ __launch_bounds__(256) void kv_reduce(const float* __restrict__ kvp, unsigned short* __restrict__ kvb){
  int i = blockIdx.x*256 + threadIdx.x;   // 0 .. BATCH*65536-1
  int b = i >> 16, e = i & 65535;
  float s = 0.f;
  #pragma unroll
  for (int sp = 0; sp < NSPLIT; sp++) s += kvp[(long)(sp*BATCH + b)*65536 + e];
  kvb[i] = f2b(s);
}

// z[g] = dot(Q[g,:], ksum[b,:]) + 1e-6 ; one wave per row
__global__ __launch_bounds__(256) void zker(const unsigned short* __restrict__ Q, const float* __restrict__ ksum,
                                            float* __restrict__ z){
  int g = blockIdx.x*4 + (threadIdx.x >> 6);
  int lane = threadIdx.x & 63;
  int b = g >> 12;
  u16x4 qv = *(const u16x4*)(Q + (long)g*DIM + lane*4);
  const float* kp = ksum + b*DIM + lane*4;
  float s = b2f(qv[0])*kp[0] + b2f(qv[1])*kp[1] + b2f(qv[2])*kp[2] + b2f(qv[3])*kp[3];
  #pragma unroll
  for (int o = 1; o < 64; o <<= 1) s += __shfl_xor(s, o);
  if (lane == 0) z[g] = s + 1e-6f;
}

// out[g][h] = (sum_d Q[g][d]*kvb[h][d]) / z[g]   (fp32 out)
__global__ __launch_bounds__(256) void out_ker(const unsigned short* __restrict__ Q, const unsigned short* __restrict__ kvb,
                                               const float* __restrict__ z, float* __restrict__ out){
  __shared__ unsigned short lA[128*128], lB[128*128];
  int lt = blockIdx.x, ht = blockIdx.y, b = blockIdx.z;
  int tid = threadIdx.x, lane = tid & 63, w = tid >> 6, wr = w >> 1, wc = w & 1;
  const unsigned short* A = Q + ((long)b*SEQ + (long)lt*128)*DIM;
  const unsigned short* B = kvb + b*DIM*DIM + ht*128*DIM;
  f32x4 acc[4][4] = {};
  gemm256<false,false>(A, DIM, B, DIM, tid, lane, wr, wc, lA, lB, acc);
  int r0 = lane & 15, rg = lane >> 4;
  #pragma unroll
  for (int m = 0; m < 4; m++)
    #pragma unroll
    for (int r = 0; r < 4; r++){
      long g = (long)b*SEQ + lt*128 + wr*64 + m*16 + rg*4 + r;
      float inv = 1.0f / z[g];
      #pragma unroll
      for (int n = 0; n < 4; n++){
        int col = ht*128 + wc*64 + n*16 + r0;
        out[g*DIM + col] = acc[m][n][r] * inv;
      }
    }
}

extern "C" void kernel_launch(void* const* d_in, const int* in_sizes, int n_in,
                              void* d_out, int out_size, void* d_ws, size_t ws_size,
                              hipStream_t stream){
  const float* q  = (const float*)d_in[0];
  const float* k  = (const float*)d_in[1];
  const float* v  = (const float*)d_in[2];
  const float* Wq = (const float*)d_in[3];
  const float* bq = (const float*)d_in[4];
  const float* Wk = (const float*)d_in[5];
  const float* bk = (const float*)d_in[6];
  const float* Wv = (const float*)d_in[7];
  const float* bv = (const float*)d_in[8];
  float* out = (float*)d_out;

  char* ws = (char*)d_ws;
  size_t off = 0;
  auto alloc = [&](size_t bytes){ void* p = ws + off; off += (bytes + 255) & ~(size_t)255; return p; };
  unsigned short* Q   = (unsigned short*)alloc((size_t)MTOT*DIM*2);          // 16 MiB
  unsigned short* Kt  = (unsigned short*)alloc((size_t)BATCH*DIM*SEQ*2);     // 16 MiB
  unsigned short* Vt  = (unsigned short*)alloc((size_t)BATCH*DIM*SEQ*2);     // 16 MiB
  unsigned short* Wt  = (unsigned short*)alloc((size_t)3*DIM*DIM*2);         // 384 KiB
  float*          kvp = (float*)alloc((size_t)NSPLIT*BATCH*DIM*DIM*4);       // 16 MiB
  unsigned short* kvb = (unsigned short*)alloc((size_t)BATCH*DIM*DIM*2);     // 1 MiB
  float*          ksum= (float*)alloc((size_t)BATCH*DIM*4);                  // 8 KiB
  float*          zb  = (float*)alloc((size_t)MTOT*4);                       // 128 KiB

  hipMemsetAsync(ksum, 0, (size_t)BATCH*DIM*4, stream);   // only remaining atomic target

  hipLaunchKernelGGL(prep_wt,     dim3(768),        dim3(256), 0, stream, Wq, Wk, Wv, Wt);
  hipLaunchKernelGGL(proj_all_ker,dim3(32,2,24),    dim3(256), 0, stream, q, k, v, Wt, bq, bk, bv, Q, Kt, Vt, ksum);
  hipLaunchKernelGGL(kv_ker,      dim3(4,NSPLIT,8), dim3(256), 0, stream, Vt, Kt, kvp);
  hipLaunchKernelGGL(kv_reduce,   dim3(2048),       dim3(256), 0, stream, kvp, kvb);
  hipLaunchKernelGGL(zker,        dim3(8192),       dim3(256), 0, stream, Q, ksum, zb);
  hipLaunchKernelGGL(out_ker,     dim3(32,2,8),     dim3(256), 0, stream, Q, kvb, zb, out);
}